// Round 1
// baseline (97.142 us; speedup 1.0000x reference)
//
#include <hip/hip_runtime.h>
#include <stdint.h>

#define N     8192
#define KDIM  256
#define BM    128
#define BK    64
#define MARGIN 0.5f

typedef __bf16 bf16x8 __attribute__((ext_vector_type(8)));
typedef float  f32x4  __attribute__((ext_vector_type(4)));

// fp32 -> bf16 round-to-nearest-even (manual, data has no NaN/Inf)
__device__ __forceinline__ unsigned short f2bf(float f) {
    unsigned u = __float_as_uint(f);
    unsigned r = u + 0x7fffu + ((u >> 16) & 1u);
    return (unsigned short)(r >> 16);
}
__device__ __forceinline__ float bf2f(unsigned short s) {
    return __uint_as_float(((unsigned)s) << 16);
}

// async global->LDS, 16 bytes per lane; LDS dest is wave-uniform base + lane*16
__device__ __forceinline__ void async_copy16(const void* g, void* l) {
    __builtin_amdgcn_global_load_lds(
        (__attribute__((address_space(1))) void*)(g),
        (__attribute__((address_space(3))) void*)(l),
        16, 0, 0);
}

// ---------------------------------------------------------------------------
// Prepass: fp32 -> bf16 (RNE) into ws, and per-row sum of bf16(x)^2 in fp32.
// One wave per row: 64 lanes x 4 elems (float4 in, ushort4 out).
// ---------------------------------------------------------------------------
__global__ __launch_bounds__(256) void prep_kernel(
        const float* __restrict__ X, unsigned short* __restrict__ Xb,
        float* __restrict__ sq) {
    int row  = blockIdx.x * 4 + (threadIdx.x >> 6);
    int lane = threadIdx.x & 63;

    const float4* src = (const float4*)(X + (size_t)row * KDIM) + lane;
    float4 v = *src;

    ushort4 o;
    o.x = f2bf(v.x); o.y = f2bf(v.y); o.z = f2bf(v.z); o.w = f2bf(v.w);
    float a = bf2f(o.x), b = bf2f(o.y), c = bf2f(o.z), d = bf2f(o.w);
    float ss = a * a + b * b + c * c + d * d;

    *((ushort4*)(Xb + (size_t)row * KDIM) + lane) = o;

    #pragma unroll
    for (int off = 32; off > 0; off >>= 1) ss += __shfl_down(ss, off, 64);
    if (lane == 0) sq[row] = ss;
}

// ---------------------------------------------------------------------------
// Main: upper-triangle 128x128 block tiles of the Gram matrix via
// mfma_f32_16x16x32_bf16, fused contrastive-loss epilogue, per-block partial.
// ---------------------------------------------------------------------------
__global__ __launch_bounds__(256) void loss_kernel(
        const unsigned short* __restrict__ Xb, const float* __restrict__ sq,
        const int* __restrict__ tgt, float* __restrict__ partials) {
    const int bj = blockIdx.x;   // col tile
    const int bi = blockIdx.y;   // row tile
    const int linear = bi * 64 + bj;

    if (bj < bi) {               // lower triangle: contribute 0 (ws is poisoned)
        if (threadIdx.x == 0) partials[linear] = 0.0f;
        return;
    }

    __shared__ __align__(16) unsigned short As[BM * BK];
    __shared__ __align__(16) unsigned short Bs[BM * BK];
    __shared__ float sqa_s[BM], sqb_s[BM];
    __shared__ int   ta_s[BM],  tb_s[BM];
    __shared__ float wsum[4];

    const int tid  = threadIdx.x;
    const int wave = tid >> 6;
    const int lane = tid & 63;

    // epilogue metadata loads (visible after first K-loop barrier)
    if (tid < 128) {
        sqa_s[tid] = sq[bi * BM + tid];
        ta_s[tid]  = tgt[bi * BM + tid];
    } else {
        int r = tid - 128;
        sqb_s[r] = sq[bj * BM + r];
        tb_s[r]  = tgt[bj * BM + r];
    }

    const int frow  = lane & 15;   // fragment row/col within 16
    const int fquad = lane >> 4;   // 0..3

    f32x4 acc[4][4];
    #pragma unroll
    for (int im = 0; im < 4; ++im)
        #pragma unroll
        for (int in = 0; in < 4; ++in)
            acc[im][in] = (f32x4){0.f, 0.f, 0.f, 0.f};

    const int wm = (wave >> 1) * 64;   // wave's 64x64 sub-tile
    const int wn = (wave & 1) * 64;

    const size_t rowA0 = (size_t)bi * BM;
    const size_t rowB0 = (size_t)bj * BM;

    // staging lane decomposition: 8 rows x 8 granules (16 B each) per issue
    const int lr = lane >> 3;               // row within 8-row group
    const int cg = (lane & 7) ^ lr;         // XOR-swizzled global granule

    for (int kt = 0; kt < KDIM / BK; ++kt) {
        const int k0 = kt * BK;
        #pragma unroll
        for (int q = 0; q < 4; ++q) {
            const int r0 = (wave * 4 + q) * 8;           // 8-row group base
            const unsigned short* gA =
                Xb + (rowA0 + r0 + lr) * KDIM + k0 + cg * 8;
            async_copy16(gA, (char*)As + r0 * 128);
            const unsigned short* gB =
                Xb + (rowB0 + r0 + lr) * KDIM + k0 + cg * 8;
            async_copy16(gB, (char*)Bs + r0 * 128);
        }
        __syncthreads();

        #pragma unroll
        for (int s = 0; s < 2; ++s) {
            const int gi = s * 4 + fquad;   // k-granule index within BK
            bf16x8 af[4], bfr[4];
            #pragma unroll
            for (int im = 0; im < 4; ++im) {
                int m = wm + im * 16 + frow;
                af[im] = *(const bf16x8*)((const char*)As +
                          m * 128 + ((gi ^ (m & 7)) * 16));
            }
            #pragma unroll
            for (int in = 0; in < 4; ++in) {
                int n = wn + in * 16 + frow;
                bfr[in] = *(const bf16x8*)((const char*)Bs +
                           n * 128 + ((gi ^ (n & 7)) * 16));
            }
            #pragma unroll
            for (int im = 0; im < 4; ++im)
                #pragma unroll
                for (int in = 0; in < 4; ++in)
                    acc[im][in] = __builtin_amdgcn_mfma_f32_16x16x32_bf16(
                        af[im], bfr[in], acc[im][in], 0, 0, 0);
        }
        __syncthreads();
    }

    // epilogue: C/D mapping col=lane&15, row=(lane>>4)*4+reg
    float lsum = 0.0f;
    const bool diag = (bi == bj);
    #pragma unroll
    for (int im = 0; im < 4; ++im) {
        #pragma unroll
        for (int in = 0; in < 4; ++in) {
            #pragma unroll
            for (int r = 0; r < 4; ++r) {
                int rl = wm + im * 16 + fquad * 4 + r;
                int cl = wn + in * 16 + frow;
                float g = acc[im][in][r];
                float d = sqa_s[rl] + sqb_s[cl] - 2.0f * g;
                float c = (ta_s[rl] == tb_s[cl]) ? d
                                                 : fmaxf(MARGIN - d, 0.0f);
                float w = 2.0f;
                if (diag) w = (rl < cl) ? 2.0f : ((rl == cl) ? 1.0f : 0.0f);
                lsum += w * c;
            }
        }
    }

    #pragma unroll
    for (int off = 32; off > 0; off >>= 1) lsum += __shfl_down(lsum, off, 64);
    if (lane == 0) wsum[wave] = lsum;
    __syncthreads();
    if (tid == 0) partials[linear] = wsum[0] + wsum[1] + wsum[2] + wsum[3];
}

// ---------------------------------------------------------------------------
// Final: reduce 4096 block partials deterministically, scale, write d_out[0].
// ---------------------------------------------------------------------------
__global__ __launch_bounds__(256) void reduce_kernel(
        const float* __restrict__ partials, float* __restrict__ out,
        int n, float scale) {
    float s = 0.0f;
    for (int i = threadIdx.x; i < n; i += 256) s += partials[i];
    __shared__ float w[4];
    #pragma unroll
    for (int off = 32; off > 0; off >>= 1) s += __shfl_down(s, off, 64);
    int wave = threadIdx.x >> 6, lane = threadIdx.x & 63;
    if (lane == 0) w[wave] = s;
    __syncthreads();
    if (threadIdx.x == 0) out[0] = (w[0] + w[1] + w[2] + w[3]) * scale;
}

extern "C" void kernel_launch(void* const* d_in, const int* in_sizes, int n_in,
                              void* d_out, int out_size, void* d_ws, size_t ws_size,
                              hipStream_t stream) {
    (void)in_sizes; (void)n_in; (void)out_size; (void)ws_size;
    const float* X   = (const float*)d_in[0];
    const int*   tgt = (const int*)d_in[1];   // harness passes integers as int32

    unsigned short* Xb = (unsigned short*)d_ws;                 // 4 MB bf16
    float* sq       = (float*)((char*)d_ws + (size_t)N * KDIM * 2);
    float* partials = sq + N;                                    // 4096 floats

    prep_kernel<<<N / 4, 256, 0, stream>>>(X, Xb, sq);
    loss_kernel<<<dim3(64, 64), 256, 0, stream>>>(Xb, sq, tgt, partials);

    const float scale = (float)(1.0 / ((double)N * ((double)N - 1.0) * 2.0));
    reduce_kernel<<<1, 256, 0, stream>>>(partials, (float*)d_out, 64 * 64, scale);
}